// Round 4
// baseline (866.137 us; speedup 1.0000x reference)
//
#include <hip/hip_runtime.h>
#include <hip/hip_bf16.h>

#define IMG 256
#define SPLIT 4  // row-block work-items per face

struct __align__(16) FaceRec { float4 r0; float4 r1; };
// r0 = (v0x, v0y, v1x, v1y)
// r1 = (v2x, v2y, bits(bbox: ix0|iy0<<8|ix1<<16|iy1<<24), bits(meta: tws-3 | b<<2))

// ws layout: [0..63] counters ([0]=queue, [1]=validCount); [64..] ndc float2*B*V;
//            [recOff..] FaceRec * (#valid faces)

// Fused: zero output + zero counters + project vertices (numpy fp32 op order,
// every op individually rounded — no fma contraction anywhere).
__global__ void init_kernel(const float* __restrict__ verts,
                            const float* __restrict__ cams,
                            float4* __restrict__ out4, int n4,
                            unsigned* __restrict__ counters,
                            float2* __restrict__ ndc, int BV, int V) {
    int i = blockIdx.x * blockDim.x + threadIdx.x;
    if (i < n4) out4[i] = make_float4(0.f, 0.f, 0.f, 0.f);
    if (i < 2)  counters[i] = 0u;
    if (i < BV) {
        int b = i / V;
        float f  = __fadd_rn(__fmul_rn(1.0f, cams[b * 3 + 0]), 0.0f);
        float cx = cams[b * 3 + 1];
        float cy = cams[b * 3 + 2];
        float image_size = __fmul_rn(cams[1], 2.0f);  // cam[0,1] * 2.0
        float x = verts[3 * i + 0];
        float y = verts[3 * i + 1];
        float z = __fadd_rn(verts[3 * i + 2], 0.0f);
        float px = __fadd_rn(__fdiv_rn(__fmul_rn(f, x), z), cx);
        float py = __fadd_rn(__fdiv_rn(__fmul_rn(f, y), z), cy);
        float nx = __fsub_rn(__fmul_rn(__fdiv_rn(px, image_size), 2.0f), 1.0f);
        float ny = __fsub_rn(__fmul_rn(__fdiv_rn(py, image_size), 2.0f), 1.0f);
        ndc[i] = make_float2(nx, ny);
    }
}

// Per-face setup: area/bbox cull, tile-shape choice, compact valid faces into
// a flat record array via atomic append (order irrelevant — idempotent max).
__global__ void setup_kernel(const int* __restrict__ faces,
                             const float2* __restrict__ ndc,
                             unsigned* __restrict__ counters,
                             FaceRec* __restrict__ recs,
                             int B, int V, int F) {
    int i = blockIdx.x * blockDim.x + threadIdx.x;
    if (i >= B * F) return;
    int b = i / F;
    const int* fp = faces + (size_t)i * 3;
    const float2* nb = ndc + (size_t)b * V;
    float2 v0 = nb[fp[0]], v1 = nb[fp[1]], v2 = nb[fp[2]];

    // area, exact np fp32 order
    float area = __fsub_rn(
        __fmul_rn(__fsub_rn(v1.x, v0.x), __fsub_rn(v2.y, v0.y)),
        __fmul_rn(__fsub_rn(v1.y, v0.y), __fsub_rn(v2.x, v0.x)));
    if (!(fabsf(area) > 1e-12f)) return;

    // Conservative bbox: center(i) = (2i+1)/256-1 => i = 128*v + 127.5
    float xmn = fminf(v0.x, fminf(v1.x, v2.x));
    float xmx = fmaxf(v0.x, fmaxf(v1.x, v2.x));
    float ymn = fminf(v0.y, fminf(v1.y, v2.y));
    float ymx = fmaxf(v0.y, fmaxf(v1.y, v2.y));
    int ix0 = max(0,       (int)floorf(xmn * 128.0f + 127.5f) - 1);
    int ix1 = min(IMG - 1, (int)ceilf (xmx * 128.0f + 127.5f) + 1);
    int iy0 = max(0,       (int)floorf(ymn * 128.0f + 127.5f) - 1);
    int iy1 = min(IMG - 1, (int)ceilf (ymx * 128.0f + 127.5f) + 1);
    if (ix1 < ix0 || iy1 < iy0) return;
    int W = ix1 - ix0 + 1, H = iy1 - iy0 + 1;

    // Lane tile shape (TW x TH, TW*TH = 64) minimizing wave-iterations.
    int tws = 6, bestIt = ((W + 63) >> 6) * H;
    int it;
    it = ((W + 31) >> 5) * ((H + 1) >> 1); if (it < bestIt) { bestIt = it; tws = 5; }
    it = ((W + 15) >> 4) * ((H + 3) >> 2); if (it < bestIt) { bestIt = it; tws = 4; }
    it = ((W + 7)  >> 3) * ((H + 7) >> 3); if (it < bestIt) { bestIt = it; tws = 3; }

    unsigned pos = atomicAdd(&counters[1], 1u);
    FaceRec r;
    r.r0 = make_float4(v0.x, v0.y, v1.x, v1.y);
    unsigned bbox = (unsigned)ix0 | ((unsigned)iy0 << 8)
                  | ((unsigned)ix1 << 16) | ((unsigned)iy1 << 24);
    unsigned meta = (unsigned)(tws - 3) | ((unsigned)b << 2);
    r.r1 = make_float4(v2.x, v2.y, __uint_as_float(bbox), __uint_as_float(meta));
    recs[pos] = r;
}

// Persistent waves pull (face, sub) work items from a global queue: perfect
// load balance over the heavy-tailed bbox-area distribution. Inner loop is
// bit-identical to the verified R1/R2 kernel.
__global__ __launch_bounds__(256) void raster_kernel(
        unsigned* __restrict__ counters, const FaceRec* __restrict__ recs,
        float* __restrict__ out) {
    int lane = threadIdx.x & 63;
    unsigned total = counters[1] * SPLIT;

    for (;;) {
        int wq;
        if (lane == 0) wq = (int)atomicAdd(&counters[0], 1u);
        wq = __shfl(wq, 0, 64);
        if ((unsigned)wq >= total) break;
        unsigned fi = (unsigned)wq >> 2, sub = (unsigned)wq & 3;

        float4 r0 = recs[fi].r0;
        float4 r1 = recs[fi].r1;
        float2 v0 = make_float2(r0.x, r0.y);
        float2 v1 = make_float2(r0.z, r0.w);
        float2 v2 = make_float2(r1.x, r1.y);
        unsigned bbox = __float_as_uint(r1.z);
        unsigned meta = __float_as_uint(r1.w);
        int ix0 = bbox & 255, iy0 = (bbox >> 8) & 255;
        int ix1 = (bbox >> 16) & 255, iy1 = bbox >> 24;
        int tws = (meta & 3) + 3, b = meta >> 2;
        int TW = 1 << tws, TH = 64 >> tws;
        int dx = lane & (TW - 1), dy = lane >> tws;

        // Edge deltas recomputed with the identical rounded subtraction.
        float e0x = __fsub_rn(v2.x, v1.x), e0y = __fsub_rn(v2.y, v1.y);
        float e1x = __fsub_rn(v0.x, v2.x), e1y = __fsub_rn(v0.y, v2.y);
        float e2x = __fsub_rn(v1.x, v0.x), e2y = __fsub_rn(v1.y, v0.y);

        float* outb = out + (size_t)b * IMG * IMG;
        float pxStep = (float)TW * 0.0078125f;  // exact power of two

        for (int ty = iy0 + (int)sub * TH; ty <= iy1; ty += SPLIT * TH) {
            int y = ty + dy;
            bool yok = (y <= iy1);
            float py = (float)(2 * y + 1) * 0.00390625f - 1.0f;  // exact
            float t0 = __fmul_rn(__fsub_rn(py, v1.y), e0x);
            float t1 = __fmul_rn(__fsub_rn(py, v2.y), e1x);
            float t2 = __fmul_rn(__fsub_rn(py, v0.y), e2x);
            float* p = outb + y * IMG + ix0 + dx;
            int x = ix0 + dx;
            float px = (float)(2 * x + 1) * 0.00390625f - 1.0f;  // exact
            for (int tx = ix0; tx <= ix1; tx += TW) {
                float w0 = __fsub_rn(__fmul_rn(__fsub_rn(px, v1.x), e0y), t0);
                float w1 = __fsub_rn(__fmul_rn(__fsub_rn(px, v2.x), e1y), t1);
                float w2 = __fsub_rn(__fmul_rn(__fsub_rn(px, v0.x), e2y), t2);
                float mn = fminf(w0, fminf(w1, w2));   // v_min3
                float mx = fmaxf(w0, fmaxf(w1, w2));   // v_max3
                bool inside = (mn >= 0.f) | (mx <= 0.f);
                if (inside & yok & (x <= ix1)) *p = 1.0f;
                px += pxStep;  // exact, bit-identical to direct eval
                x  += TW;
                p  += TW;
            }
        }
    }
}

extern "C" void kernel_launch(void* const* d_in, const int* in_sizes, int n_in,
                              void* d_out, int out_size, void* d_ws, size_t ws_size,
                              hipStream_t stream) {
    const float* verts = (const float*)d_in[0];
    const int*   faces = (const int*)d_in[1];
    const float* cams  = (const float*)d_in[2];
    float* out = (float*)d_out;

    int B = in_sizes[2] / 3;
    int V = in_sizes[0] / (3 * B);
    int F = in_sizes[1] / (3 * B);
    int BV = B * V, BF = B * F;

    unsigned* counters = (unsigned*)d_ws;
    float2* ndc = (float2*)((char*)d_ws + 64);
    size_t recOff = (64 + (size_t)BV * sizeof(float2) + 15) & ~(size_t)15;
    FaceRec* recs = (FaceRec*)((char*)d_ws + recOff);

    int n4 = out_size / 4;
    int initThreads = max(n4, BV);
    hipLaunchKernelGGL(init_kernel, dim3((initThreads + 255) / 256), dim3(256), 0,
                       stream, verts, cams, (float4*)d_out, n4, counters, ndc, BV, V);
    hipLaunchKernelGGL(setup_kernel, dim3((BF + 255) / 256), dim3(256), 0,
                       stream, faces, ndc, counters, recs, B, V, F);
    // Persistent grid: 8 blocks/CU * 256 CUs (queue-drained, any residency safe)
    hipLaunchKernelGGL(raster_kernel, dim3(2048), dim3(256), 0,
                       stream, counters, recs, out);
}

// Round 5
// 116.288 us; speedup vs baseline: 7.4482x; 7.4482x over previous
//
#include <hip/hip_runtime.h>
#include <hip/hip_bf16.h>

#define IMG 256
#define SPLIT 8  // row-block waves per face (static, sub-major)

struct __align__(16) FaceRec { float4 r0; float4 r1; };
// r0 = (v0x, v0y, v1x, v1y)
// r1 = (v2x, v2y, bits(bbox: ix0|iy0<<8|ix1<<16|iy1<<24), bits(meta: tws-3 | b<<2))
// invalid face -> bbox encodes iy0=1, iy1=0 (raster loop never executes)

// One kernel: zero output image AND build per-face records. Each face thread
// projects its own 3 vertices with the numpy fp32 op order (every op
// individually rounded, no fma) — deterministic, so identical to a shared
// projection pass. Then area cull, conservative bbox, lane-tile choice.
__global__ void setup_kernel(const float* __restrict__ verts,
                             const int* __restrict__ faces,
                             const float* __restrict__ cams,
                             float4* __restrict__ out4, int n4,
                             FaceRec* __restrict__ recs,
                             int B, int V, int F) {
    int i = blockIdx.x * blockDim.x + threadIdx.x;
    if (i < n4) out4[i] = make_float4(0.f, 0.f, 0.f, 0.f);
    int BF = B * F;
    if (i >= BF) return;
    int b = i / F;

    float f  = __fadd_rn(__fmul_rn(1.0f, cams[b * 3 + 0]), 0.0f);
    float cx = cams[b * 3 + 1];
    float cy = cams[b * 3 + 2];
    float image_size = __fmul_rn(cams[1], 2.0f);  // cam[0,1] * 2.0
    const float* vb = verts + (size_t)b * V * 3;
    const int* fp = faces + (size_t)i * 3;

    float vx[3], vy[3];
#pragma unroll
    for (int k = 0; k < 3; ++k) {
        const float* vp = vb + (size_t)fp[k] * 3;
        float X = vp[0], Y = vp[1];
        float Z = __fadd_rn(vp[2], 0.0f);
        float ppx = __fadd_rn(__fdiv_rn(__fmul_rn(f, X), Z), cx);
        float ppy = __fadd_rn(__fdiv_rn(__fmul_rn(f, Y), Z), cy);
        vx[k] = __fsub_rn(__fmul_rn(__fdiv_rn(ppx, image_size), 2.0f), 1.0f);
        vy[k] = __fsub_rn(__fmul_rn(__fdiv_rn(ppy, image_size), 2.0f), 1.0f);
    }

    // area, exact np fp32 order
    float area = __fsub_rn(
        __fmul_rn(__fsub_rn(vx[1], vx[0]), __fsub_rn(vy[2], vy[0])),
        __fmul_rn(__fsub_rn(vy[1], vy[0]), __fsub_rn(vx[2], vx[0])));

    FaceRec r;
    r.r0 = make_float4(vx[0], vy[0], vx[1], vy[1]);
    unsigned bbox = (1u << 8);  // empty: iy0=1, iy1=0
    unsigned meta = 0u;

    if (fabsf(area) > 1e-12f) {
        // Conservative bbox: center(i) = (2i+1)/256-1 => i = 128*v + 127.5
        float xmn = fminf(vx[0], fminf(vx[1], vx[2]));
        float xmx = fmaxf(vx[0], fmaxf(vx[1], vx[2]));
        float ymn = fminf(vy[0], fminf(vy[1], vy[2]));
        float ymx = fmaxf(vy[0], fmaxf(vy[1], vy[2]));
        int ix0 = max(0,       (int)floorf(xmn * 128.0f + 127.5f) - 1);
        int ix1 = min(IMG - 1, (int)ceilf (xmx * 128.0f + 127.5f) + 1);
        int iy0 = max(0,       (int)floorf(ymn * 128.0f + 127.5f) - 1);
        int iy1 = min(IMG - 1, (int)ceilf (ymx * 128.0f + 127.5f) + 1);
        if (ix0 <= ix1 && iy0 <= iy1) {
            int W = ix1 - ix0 + 1, H = iy1 - iy0 + 1;
            int tws = 6, bestIt = ((W + 63) >> 6) * H;
            int it;
            it = ((W + 31) >> 5) * ((H + 1) >> 1); if (it < bestIt) { bestIt = it; tws = 5; }
            it = ((W + 15) >> 4) * ((H + 3) >> 2); if (it < bestIt) { bestIt = it; tws = 4; }
            it = ((W + 7)  >> 3) * ((H + 7) >> 3); if (it < bestIt) { bestIt = it; tws = 3; }
            bbox = (unsigned)ix0 | ((unsigned)iy0 << 8)
                 | ((unsigned)ix1 << 16) | ((unsigned)iy1 << 24);
            meta = (unsigned)(tws - 3) | ((unsigned)b << 2);
        }
    }
    r.r1 = make_float4(vx[2], vy[2], __uint_as_float(bbox), __uint_as_float(meta));
    recs[i] = r;
}

// Static sub-major mapping: wave widx -> (face = widx % BF, sub = widx / BF).
// A 256-thread block holds 4 different faces; a big face's 8 subs land in 8
// widely separated blocks. Prologue = one 32B record load + decode. Inner
// loop bit-identical to the verified absmax-0 kernel.
__global__ __launch_bounds__(256) void raster_kernel(
        const FaceRec* __restrict__ recs, float* __restrict__ out, int BF) {
    int gid  = blockIdx.x * blockDim.x + threadIdx.x;
    int wave = gid >> 6;
    int lane = gid & 63;
    if (wave >= BF * SPLIT) return;
    int sub  = wave / BF;
    int fi   = wave - sub * BF;

    float4 r0 = recs[fi].r0;
    float4 r1 = recs[fi].r1;
    float2 v0 = make_float2(r0.x, r0.y);
    float2 v1 = make_float2(r0.z, r0.w);
    float2 v2 = make_float2(r1.x, r1.y);
    unsigned bbox = __float_as_uint(r1.z);
    unsigned meta = __float_as_uint(r1.w);
    int ix0 = bbox & 255, iy0 = (bbox >> 8) & 255;
    int ix1 = (bbox >> 16) & 255, iy1 = (int)(bbox >> 24);
    int tws = (int)(meta & 3) + 3, b = (int)(meta >> 2);
    int TW = 1 << tws, TH = 64 >> tws;
    int dx = lane & (TW - 1), dy = lane >> tws;

    // Edge deltas, individually rounded (matching np)
    float e0x = __fsub_rn(v2.x, v1.x), e0y = __fsub_rn(v2.y, v1.y);
    float e1x = __fsub_rn(v0.x, v2.x), e1y = __fsub_rn(v0.y, v2.y);
    float e2x = __fsub_rn(v1.x, v0.x), e2y = __fsub_rn(v1.y, v0.y);

    float* outb = out + (size_t)b * IMG * IMG;
    float pxStep = (float)TW * 0.0078125f;  // exact power of two

    for (int ty = iy0 + sub * TH; ty <= iy1; ty += SPLIT * TH) {
        int y = ty + dy;
        bool yok = (y <= iy1);
        float py = (float)(2 * y + 1) * 0.00390625f - 1.0f;  // exact
        float t0 = __fmul_rn(__fsub_rn(py, v1.y), e0x);
        float t1 = __fmul_rn(__fsub_rn(py, v2.y), e1x);
        float t2 = __fmul_rn(__fsub_rn(py, v0.y), e2x);
        float* p = outb + y * IMG + ix0 + dx;
        int x = ix0 + dx;
        float px = (float)(2 * x + 1) * 0.00390625f - 1.0f;  // exact
        for (int tx = ix0; tx <= ix1; tx += TW) {
            float w0 = __fsub_rn(__fmul_rn(__fsub_rn(px, v1.x), e0y), t0);
            float w1 = __fsub_rn(__fmul_rn(__fsub_rn(px, v2.x), e1y), t1);
            float w2 = __fsub_rn(__fmul_rn(__fsub_rn(px, v0.x), e2y), t2);
            float mn = fminf(w0, fminf(w1, w2));   // v_min3
            float mx = fmaxf(w0, fmaxf(w1, w2));   // v_max3
            bool inside = (mn >= 0.f) | (mx <= 0.f);
            if (inside & yok & (x <= ix1)) *p = 1.0f;
            px += pxStep;  // exact, bit-identical to direct eval
            x  += TW;
            p  += TW;
        }
    }
}

extern "C" void kernel_launch(void* const* d_in, const int* in_sizes, int n_in,
                              void* d_out, int out_size, void* d_ws, size_t ws_size,
                              hipStream_t stream) {
    const float* verts = (const float*)d_in[0];
    const int*   faces = (const int*)d_in[1];
    const float* cams  = (const float*)d_in[2];
    float* out = (float*)d_out;

    int B = in_sizes[2] / 3;
    int V = in_sizes[0] / (3 * B);
    int F = in_sizes[1] / (3 * B);
    int BF = B * F;

    FaceRec* recs = (FaceRec*)d_ws;  // BF * 32B

    int n4 = out_size / 4;
    int setupThreads = max(n4, BF);
    hipLaunchKernelGGL(setup_kernel, dim3((setupThreads + 255) / 256), dim3(256), 0,
                       stream, verts, faces, cams, (float4*)d_out, n4, recs, B, V, F);

    long long nthreads = (long long)BF * SPLIT * 64;
    hipLaunchKernelGGL(raster_kernel, dim3((nthreads + 255) / 256), dim3(256), 0,
                       stream, recs, out, BF);
}